// Round 1
// baseline (228.304 us; speedup 1.0000x reference)
//
#include <hip/hip_runtime.h>

#define Bdim 8
#define Mdim 64
#define Tdim 256
#define MTdim 320
#define Ddim 64
#define EPSF 1e-4f

// ---------------------------------------------------------------------------
// Phase 1: u[b,i,t,d] = sum_k W[i,t,d,k] * cat[b,t,k]
// cat[b,t,k] = t < 64 ? M_emb[b,t,k] : Ht_n[b,t-64,k]
// Block = 256 threads = 4 waves; each wave owns one (i,t) tile; lane = d.
// Each lane streams its W row (64 floats) as float4; cat reads are
// wave-uniform -> scalar loads. 8 batch accumulators in registers.
// ---------------------------------------------------------------------------
__global__ __launch_bounds__(256) void u_kernel(
    const float* __restrict__ M_emb,
    const float* __restrict__ Ht,
    const float* __restrict__ W,
    float* __restrict__ u,
    int i0, int icap)
{
    const int ii = blockIdx.y;          // i within chunk
    const int i  = i0 + ii;
    const int j  = __builtin_amdgcn_readfirstlane((int)(threadIdx.x >> 6));
    const int t  = blockIdx.x * 4 + j;  // 0..319, wave-uniform
    const int d  = threadIdx.x & 63;    // lane

    const float* wrow = W + ((((size_t)i * MTdim + t) * Ddim + d) << 6);

    // wave-uniform cat row pointers, one per batch
    const float* cb[Bdim];
#pragma unroll
    for (int b = 0; b < Bdim; ++b) {
        cb[b] = (t < Mdim)
            ? (M_emb + (((size_t)b * Mdim + t) << 6))
            : (Ht   + (((size_t)b * Tdim + (t - Mdim)) << 6));
    }

    float acc[Bdim];
#pragma unroll
    for (int b = 0; b < Bdim; ++b) acc[b] = 0.0f;

#pragma unroll 4
    for (int k4 = 0; k4 < 16; ++k4) {
        const float4 w = *reinterpret_cast<const float4*>(wrow + (k4 << 2));
#pragma unroll
        for (int b = 0; b < Bdim; ++b) {
            const float* c = cb[b] + (k4 << 2);
            float a = acc[b];
            a = fmaf(w.x, c[0], a);
            a = fmaf(w.y, c[1], a);
            a = fmaf(w.z, c[2], a);
            a = fmaf(w.w, c[3], a);
            acc[b] = a;
        }
    }

    // u layout: [b][ii][t][d], i-stride = icap
#pragma unroll
    for (int b = 0; b < Bdim; ++b) {
        u[((((size_t)b * icap + ii) * MTdim + t) << 6) + d] = acc[b];
    }
}

// ---------------------------------------------------------------------------
// Phase 2: 3 routing iterations, one block per (b,i). u slice is [320][64].
// ---------------------------------------------------------------------------
__global__ __launch_bounds__(256) void iter_kernel(
    const float* __restrict__ u,
    const float* __restrict__ m_init,
    float* __restrict__ out,
    int i0, int icap)
{
    const int ii  = blockIdx.x;
    const int i   = i0 + ii;
    const int b   = blockIdx.y;
    const int tid = (int)threadIdx.x;
    const int d   = tid & 63;
    const int tg  = tid >> 6;

    const float* ub = u + ((((size_t)b * icap + ii) * MTdim) << 6);

    __shared__ __align__(16) float m_lds[Ddim];
    __shared__ float e_lds[MTdim];
    __shared__ float red[256];
    __shared__ float sc_max, sc_sum;

    if (tid < Ddim)
        m_lds[tid] = m_init[(((size_t)b * Mdim + i) << 6) + tid];
    __syncthreads();

    for (int iter = 0; iter < 3; ++iter) {
        // ---- pass A: logits b_t = dot(m, u[t,:]) -------------------------
        float bt0 = 0.0f, bt1 = 0.0f;
        {
            const float* r0 = ub + ((size_t)tid << 6);
#pragma unroll
            for (int k4 = 0; k4 < 16; ++k4) {
                float4 uv = *reinterpret_cast<const float4*>(r0 + (k4 << 2));
                float4 mv = *reinterpret_cast<const float4*>(&m_lds[k4 << 2]);
                bt0 = fmaf(uv.x, mv.x, bt0);
                bt0 = fmaf(uv.y, mv.y, bt0);
                bt0 = fmaf(uv.z, mv.z, bt0);
                bt0 = fmaf(uv.w, mv.w, bt0);
            }
        }
        if (tid < 64) {
            const float* r1 = ub + ((size_t)(256 + tid) << 6);
#pragma unroll
            for (int k4 = 0; k4 < 16; ++k4) {
                float4 uv = *reinterpret_cast<const float4*>(r1 + (k4 << 2));
                float4 mv = *reinterpret_cast<const float4*>(&m_lds[k4 << 2]);
                bt1 = fmaf(uv.x, mv.x, bt1);
                bt1 = fmaf(uv.y, mv.y, bt1);
                bt1 = fmaf(uv.z, mv.z, bt1);
                bt1 = fmaf(uv.w, mv.w, bt1);
            }
        }
        e_lds[tid] = bt0;
        if (tid < 64) e_lds[256 + tid] = bt1;
        __syncthreads();

        // ---- softmax max ------------------------------------------------
        if (tid < 64) {
            float mx = e_lds[tid];
            mx = fmaxf(mx, e_lds[tid + 64]);
            mx = fmaxf(mx, e_lds[tid + 128]);
            mx = fmaxf(mx, e_lds[tid + 192]);
            mx = fmaxf(mx, e_lds[tid + 256]);
#pragma unroll
            for (int off = 32; off >= 1; off >>= 1)
                mx = fmaxf(mx, __shfl_xor(mx, off, 64));
            if (tid == 0) sc_max = mx;
        }
        __syncthreads();
        const float bmax = sc_max;

        float e0 = expf(bt0 - bmax);
        e_lds[tid] = e0;
        if (tid < 64) e_lds[256 + tid] = expf(bt1 - bmax);
        __syncthreads();

        // ---- softmax sum ------------------------------------------------
        if (tid < 64) {
            float sm = e_lds[tid] + e_lds[tid + 64] + e_lds[tid + 128]
                     + e_lds[tid + 192] + e_lds[tid + 256];
#pragma unroll
            for (int off = 32; off >= 1; off >>= 1)
                sm += __shfl_xor(sm, off, 64);
            if (tid == 0) sc_sum = sm;
        }
        __syncthreads();
        const float inv_sum = 1.0f / sc_sum;

        // ---- pass B: s[d] = tanh( (sum_t e_t * u[t,d]) / sum_e ) --------
        float acc = 0.0f;
        for (int t = tg; t < MTdim; t += 4) {
            acc = fmaf(e_lds[t], ub[((size_t)t << 6) + d], acc);
        }
        red[(tg << 6) + d] = acc;
        __syncthreads();

        if (tid < 64) {
            float sraw = (red[tid] + red[64 + tid] + red[128 + tid]
                        + red[192 + tid]) * inv_sum;
            float s  = tanhf(sraw);
            float ss = s * s;
#pragma unroll
            for (int off = 32; off >= 1; off >>= 1)
                ss += __shfl_xor(ss, off, 64);
            float n  = sqrtf(ss) + EPSF;
            float n2 = n * n;
            m_lds[tid] = (n2 / (1.0f + n2)) * (s / n);
        }
        __syncthreads();
    }

    if (tid < 64)
        out[(((size_t)b * Mdim + i) << 6) + tid] = m_lds[tid];
}

// ---------------------------------------------------------------------------
extern "C" void kernel_launch(void* const* d_in, const int* in_sizes, int n_in,
                              void* d_out, int out_size, void* d_ws, size_t ws_size,
                              hipStream_t stream) {
    const float* M_emb  = (const float*)d_in[0];
    const float* Ht     = (const float*)d_in[1];
    const float* m_init = (const float*)d_in[2];
    const float* W      = (const float*)d_in[3];
    float* out = (float*)d_out;
    float* u   = (float*)d_ws;

    const size_t per_i = (size_t)Bdim * MTdim * Ddim * sizeof(float); // 655360 B
    int icap = (int)(ws_size / per_i);
    if (icap > Mdim) icap = Mdim;
    if (icap < 1) icap = 1;   // assume ws_size >= 640 KB

    for (int i0 = 0; i0 < Mdim; i0 += icap) {
        int ic = Mdim - i0 < icap ? Mdim - i0 : icap;
        dim3 g1(MTdim / 4, ic);
        u_kernel<<<g1, dim3(256), 0, stream>>>(M_emb, Ht, W, u, i0, icap);
        dim3 g2(ic, Bdim);
        iter_kernel<<<g2, dim3(256), 0, stream>>>(u, m_init, out, i0, icap);
    }
}

// Round 2
// 170.840 us; speedup vs baseline: 1.3364x; 1.3364x over previous
//
#include <hip/hip_runtime.h>

#define Bdim 8
#define Mdim 64
#define Tdim 256
#define MTdim 320
#define Ddim 64
#define EPSF 1e-4f

// ---------------------------------------------------------------------------
// Phase 1: u[b,i,t,d] = sum_k W[i,t,d,k] * cat[b,t,k]   (unchanged from R1)
// ---------------------------------------------------------------------------
__global__ __launch_bounds__(256) void u_kernel(
    const float* __restrict__ M_emb,
    const float* __restrict__ Ht,
    const float* __restrict__ W,
    float* __restrict__ u,
    int i0, int icap)
{
    const int ii = blockIdx.y;
    const int i  = i0 + ii;
    const int j  = __builtin_amdgcn_readfirstlane((int)(threadIdx.x >> 6));
    const int t  = blockIdx.x * 4 + j;
    const int d  = threadIdx.x & 63;

    const float* wrow = W + ((((size_t)i * MTdim + t) * Ddim + d) << 6);

    const float* cb[Bdim];
#pragma unroll
    for (int b = 0; b < Bdim; ++b) {
        cb[b] = (t < Mdim)
            ? (M_emb + (((size_t)b * Mdim + t) << 6))
            : (Ht   + (((size_t)b * Tdim + (t - Mdim)) << 6));
    }

    float acc[Bdim];
#pragma unroll
    for (int b = 0; b < Bdim; ++b) acc[b] = 0.0f;

#pragma unroll 4
    for (int k4 = 0; k4 < 16; ++k4) {
        const float4 w = *reinterpret_cast<const float4*>(wrow + (k4 << 2));
#pragma unroll
        for (int b = 0; b < Bdim; ++b) {
            const float* c = cb[b] + (k4 << 2);
            float a = acc[b];
            a = fmaf(w.x, c[0], a);
            a = fmaf(w.y, c[1], a);
            a = fmaf(w.z, c[2], a);
            a = fmaf(w.w, c[3], a);
            acc[b] = a;
        }
    }

#pragma unroll
    for (int b = 0; b < Bdim; ++b) {
        u[((((size_t)b * icap + ii) * MTdim + t) << 6) + d] = acc[b];
    }
}

// ---------------------------------------------------------------------------
// Phase 2 v2: one block of 320 threads per (b,i); thread t holds u[t,0:63]
// in registers for all 3 iterations. u read from global exactly once.
// ---------------------------------------------------------------------------
__device__ __forceinline__ float4 shfl_xor4(float4 v, int m) {
    float4 r;
    r.x = __shfl_xor(v.x, m, 64);
    r.y = __shfl_xor(v.y, m, 64);
    r.z = __shfl_xor(v.z, m, 64);
    r.w = __shfl_xor(v.w, m, 64);
    return r;
}
__device__ __forceinline__ float4 add4(float4 a, float4 b) {
    float4 r; r.x = a.x + b.x; r.y = a.y + b.y; r.z = a.z + b.z; r.w = a.w + b.w;
    return r;
}

__global__ __launch_bounds__(320) void iter_kernel(
    const float* __restrict__ u,
    const float* __restrict__ m_init,
    float* __restrict__ out,
    int i0, int icap)
{
    const int ii   = blockIdx.x;
    const int i    = i0 + ii;
    const int b    = blockIdx.y;
    const int tid  = (int)threadIdx.x;   // 0..319 == row t
    const int lane = tid & 63;
    const int w    = tid >> 6;           // 0..4

    const float* ub = u + ((((size_t)b * icap + ii) * MTdim) << 6);

    __shared__ __align__(16) float m_lds[Ddim];
    __shared__ float wmax[5], wsum[5];
    __shared__ float partial[5 * 64];

    // one-time register fill: row t of the u slice (64 floats)
    float4 u4[16];
    {
        const float* row = ub + ((size_t)tid << 6);
#pragma unroll
        for (int k4 = 0; k4 < 16; ++k4)
            u4[k4] = *reinterpret_cast<const float4*>(row + (k4 << 2));
    }

    if (tid < Ddim)
        m_lds[tid] = m_init[(((size_t)b * Mdim + i) << 6) + tid];
    __syncthreads();

    for (int iter = 0; iter < 3; ++iter) {
        // ---- pass A: logit bt = dot(m, u_row) — lane-local ---------------
        float bt = 0.0f;
#pragma unroll
        for (int k4 = 0; k4 < 16; ++k4) {
            float4 mv = *reinterpret_cast<const float4*>(&m_lds[k4 << 2]);
            bt = fmaf(u4[k4].x, mv.x, bt);
            bt = fmaf(u4[k4].y, mv.y, bt);
            bt = fmaf(u4[k4].z, mv.z, bt);
            bt = fmaf(u4[k4].w, mv.w, bt);
        }

        // ---- block max over 320 logits ----------------------------------
        float mx = bt;
#pragma unroll
        for (int off = 1; off < 64; off <<= 1)
            mx = fmaxf(mx, __shfl_xor(mx, off, 64));
        if (lane == 0) wmax[w] = mx;
        __syncthreads();
        const float bmax = fmaxf(fmaxf(fmaxf(wmax[0], wmax[1]),
                                       fmaxf(wmax[2], wmax[3])), wmax[4]);

        const float e = expf(bt - bmax);

        // ---- block sum of e (write partial; sync deferred) --------------
        float sm = e;
#pragma unroll
        for (int off = 1; off < 64; off <<= 1)
            sm += __shfl_xor(sm, off, 64);
        if (lane == 0) wsum[w] = sm;

        // ---- pass B: distributed reduce of e*u_row across the wave ------
        // After stage for bit k, each lane keeps the element-half selected
        // by its lane-bit k; after all 6 stages lane l holds element l.
        float4 c8[8];
#pragma unroll
        for (int jj = 0; jj < 8; ++jj) {
            const bool up = (lane & 32) != 0;
            float4 keep = up ? u4[jj + 8] : u4[jj];
            float4 give = up ? u4[jj] : u4[jj + 8];
            float4 g; g.x = give.x * e; g.y = give.y * e;
                      g.z = give.z * e; g.w = give.w * e;
            float4 r = shfl_xor4(g, 32);
            float4 o;
            o.x = fmaf(keep.x, e, r.x); o.y = fmaf(keep.y, e, r.y);
            o.z = fmaf(keep.z, e, r.z); o.w = fmaf(keep.w, e, r.w);
            c8[jj] = o;
        }
        float4 c4[4];
#pragma unroll
        for (int jj = 0; jj < 4; ++jj) {
            const bool up = (lane & 16) != 0;
            float4 keep = up ? c8[jj + 4] : c8[jj];
            float4 give = up ? c8[jj] : c8[jj + 4];
            c4[jj] = add4(keep, shfl_xor4(give, 16));
        }
        float4 c2[2];
#pragma unroll
        for (int jj = 0; jj < 2; ++jj) {
            const bool up = (lane & 8) != 0;
            float4 keep = up ? c4[jj + 2] : c4[jj];
            float4 give = up ? c4[jj] : c4[jj + 2];
            c2[jj] = add4(keep, shfl_xor4(give, 8));
        }
        float4 c1;
        {
            const bool up = (lane & 4) != 0;
            float4 keep = up ? c2[1] : c2[0];
            float4 give = up ? c2[0] : c2[1];
            c1 = add4(keep, shfl_xor4(give, 4));
        }
        float p0, p1;
        {
            const bool up = (lane & 2) != 0;
            float kx = up ? c1.z : c1.x, gx = up ? c1.x : c1.z;
            float ky = up ? c1.w : c1.y, gy = up ? c1.y : c1.w;
            p0 = kx + __shfl_xor(gx, 2, 64);
            p1 = ky + __shfl_xor(gy, 2, 64);
        }
        float s_part;
        {
            const bool up = (lane & 1) != 0;
            float k1 = up ? p1 : p0, g1 = up ? p0 : p1;
            s_part = k1 + __shfl_xor(g1, 1, 64);
        }
        partial[(w << 6) + lane] = s_part;
        __syncthreads();

        // ---- combine + tanh + squash (wave 0) ---------------------------
        if (tid < 64) {
            const float inv = 1.0f / (wsum[0] + wsum[1] + wsum[2]
                                    + wsum[3] + wsum[4]);
            float sraw = (partial[tid] + partial[64 + tid] + partial[128 + tid]
                        + partial[192 + tid] + partial[256 + tid]) * inv;
            float s  = tanhf(sraw);
            float ss = s * s;
#pragma unroll
            for (int off = 1; off < 64; off <<= 1)
                ss += __shfl_xor(ss, off, 64);
            float n = sqrtf(ss) + EPSF;
            m_lds[tid] = s * n / (1.0f + n * n);
        }
        __syncthreads();
    }

    if (tid < 64)
        out[(((size_t)b * Mdim + i) << 6) + tid] = m_lds[tid];
}

// ---------------------------------------------------------------------------
extern "C" void kernel_launch(void* const* d_in, const int* in_sizes, int n_in,
                              void* d_out, int out_size, void* d_ws, size_t ws_size,
                              hipStream_t stream) {
    const float* M_emb  = (const float*)d_in[0];
    const float* Ht     = (const float*)d_in[1];
    const float* m_init = (const float*)d_in[2];
    const float* W      = (const float*)d_in[3];
    float* out = (float*)d_out;
    float* u   = (float*)d_ws;

    const size_t per_i = (size_t)Bdim * MTdim * Ddim * sizeof(float);
    int icap = (int)(ws_size / per_i);
    if (icap > Mdim) icap = Mdim;
    if (icap < 1) icap = 1;

    for (int i0 = 0; i0 < Mdim; i0 += icap) {
        int ic = Mdim - i0 < icap ? Mdim - i0 : icap;
        dim3 g1(MTdim / 4, ic);
        u_kernel<<<g1, dim3(256), 0, stream>>>(M_emb, Ht, W, u, i0, icap);
        dim3 g2(ic, Bdim);
        iter_kernel<<<g2, dim3(320), 0, stream>>>(u, m_init, out, i0, icap);
    }
}

// Round 3
// 96.269 us; speedup vs baseline: 2.3715x; 1.7746x over previous
//
#include <hip/hip_runtime.h>

#define Bdim 8
#define Mdim 64
#define Tdim 256
#define MTdim 320
#define Ddim 64
#define EPSF 1e-4f

__device__ __forceinline__ void load_lds16(const void* g, void* l) {
    __builtin_amdgcn_global_load_lds(
        (const __attribute__((address_space(1))) void*)g,
        (__attribute__((address_space(3))) void*)l, 16, 0, 0);
}

// ---------------------------------------------------------------------------
// Phase 1 v2: u[b,i,t,d] = sum_k W[i,t,d,k] * cat[b,t,k]
// One block (4 waves) per (i,t). W tile (16 KB) staged via global_load_lds
// with XOR-swizzled content: logical 16B chunk k4 of row d is stored at
// byte d*256 + ((k4 ^ (d&7))*16). Source global address is pre-swizzled
// (rule #21: linear LDS dest + inv-swizzled source + swizzled read).
// Wave w computes batches b=2w,2w+1; lane = d; cat reads are wave-uniform.
// ---------------------------------------------------------------------------
__global__ __launch_bounds__(256) void u_kernel(
    const float* __restrict__ M_emb,
    const float* __restrict__ Ht,
    const float* __restrict__ W,
    float* __restrict__ u,
    int i0, int icap)
{
    const int t   = blockIdx.x;                  // 0..319
    const int ii  = blockIdx.y;                  // i within chunk
    const int i   = i0 + ii;
    const int tid = (int)threadIdx.x;
    const int l   = tid & 63;                    // lane
    const int w   = __builtin_amdgcn_readfirstlane(tid >> 6);  // wave 0..3

    __shared__ __align__(16) float wtile[64 * 64];   // 16 KB swizzled

    const char* wt = (const char*)(W + (((size_t)i * MTdim + t) << 12));
    char* ldsb = (char*)wtile;

    // ---- stage: wave w issues 4 instructions, each 1 KB ----
#pragma unroll
    for (int s = 0; s < 4; ++s) {
        const int r   = w * 16 + s * 4 + (l >> 4);       // row d
        const int src = (r * 256 + ((l & 15) * 16)) ^ ((r & 7) * 16);
        load_lds16(wt + src, ldsb + (w * 4096 + s * 1024));
    }

    // ---- wave-uniform cat row pointers, b = 2w, 2w+1 ----
    const int b0 = 2 * w, b1 = 2 * w + 1;
    const float* c0;
    const float* c1;
    if (t < Mdim) {
        c0 = M_emb + (((size_t)b0 * Mdim + t) << 6);
        c1 = M_emb + (((size_t)b1 * Mdim + t) << 6);
    } else {
        c0 = Ht + (((size_t)b0 * Tdim + (t - Mdim)) << 6);
        c1 = Ht + (((size_t)b1 * Tdim + (t - Mdim)) << 6);
    }

    __syncthreads();   // drains vmcnt(0) -> tile resident

    // ---- compute: lane l = row d; swizzled ds_read_b128 ----
    const int rbase = l * 256 + (l & 7) * 16;    // (A+M); addr = rbase ^ (k4*16)
    float a0 = 0.0f, a1 = 0.0f;
#pragma unroll
    for (int k4 = 0; k4 < 16; ++k4) {
        const float4 w4 = *reinterpret_cast<const float4*>(ldsb + (rbase ^ (k4 * 16)));
        const float4 p  = *reinterpret_cast<const float4*>(c0 + (k4 << 2));
        const float4 q  = *reinterpret_cast<const float4*>(c1 + (k4 << 2));
        a0 = fmaf(w4.x, p.x, a0); a0 = fmaf(w4.y, p.y, a0);
        a0 = fmaf(w4.z, p.z, a0); a0 = fmaf(w4.w, p.w, a0);
        a1 = fmaf(w4.x, q.x, a1); a1 = fmaf(w4.y, q.y, a1);
        a1 = fmaf(w4.z, q.z, a1); a1 = fmaf(w4.w, q.w, a1);
    }

    // u layout: [b][ii][t][d], i-stride = icap
    u[((((size_t)b0 * icap + ii) * MTdim + t) << 6) + l] = a0;
    u[((((size_t)b1 * icap + ii) * MTdim + t) << 6) + l] = a1;
}

// ---------------------------------------------------------------------------
// Phase 2 (unchanged from R2): one block of 320 threads per (b,i);
// thread t holds u[t,0:63] in registers for all 3 iterations.
// ---------------------------------------------------------------------------
__device__ __forceinline__ float4 shfl_xor4(float4 v, int m) {
    float4 r;
    r.x = __shfl_xor(v.x, m, 64);
    r.y = __shfl_xor(v.y, m, 64);
    r.z = __shfl_xor(v.z, m, 64);
    r.w = __shfl_xor(v.w, m, 64);
    return r;
}
__device__ __forceinline__ float4 add4(float4 a, float4 b) {
    float4 r; r.x = a.x + b.x; r.y = a.y + b.y; r.z = a.z + b.z; r.w = a.w + b.w;
    return r;
}

__global__ __launch_bounds__(320) void iter_kernel(
    const float* __restrict__ u,
    const float* __restrict__ m_init,
    float* __restrict__ out,
    int i0, int icap)
{
    const int ii   = blockIdx.x;
    const int i    = i0 + ii;
    const int b    = blockIdx.y;
    const int tid  = (int)threadIdx.x;   // 0..319 == row t
    const int lane = tid & 63;
    const int w    = tid >> 6;           // 0..4

    const float* ub = u + ((((size_t)b * icap + ii) * MTdim) << 6);

    __shared__ __align__(16) float m_lds[Ddim];
    __shared__ float wmax[5], wsum[5];
    __shared__ float partial[5 * 64];

    float4 u4[16];
    {
        const float* row = ub + ((size_t)tid << 6);
#pragma unroll
        for (int k4 = 0; k4 < 16; ++k4)
            u4[k4] = *reinterpret_cast<const float4*>(row + (k4 << 2));
    }

    if (tid < Ddim)
        m_lds[tid] = m_init[(((size_t)b * Mdim + i) << 6) + tid];
    __syncthreads();

    for (int iter = 0; iter < 3; ++iter) {
        // ---- pass A: logit bt = dot(m, u_row) — lane-local ---------------
        float bt = 0.0f;
#pragma unroll
        for (int k4 = 0; k4 < 16; ++k4) {
            float4 mv = *reinterpret_cast<const float4*>(&m_lds[k4 << 2]);
            bt = fmaf(u4[k4].x, mv.x, bt);
            bt = fmaf(u4[k4].y, mv.y, bt);
            bt = fmaf(u4[k4].z, mv.z, bt);
            bt = fmaf(u4[k4].w, mv.w, bt);
        }

        // ---- block max over 320 logits ----------------------------------
        float mx = bt;
#pragma unroll
        for (int off = 1; off < 64; off <<= 1)
            mx = fmaxf(mx, __shfl_xor(mx, off, 64));
        if (lane == 0) wmax[w] = mx;
        __syncthreads();
        const float bmax = fmaxf(fmaxf(fmaxf(wmax[0], wmax[1]),
                                       fmaxf(wmax[2], wmax[3])), wmax[4]);

        const float e = expf(bt - bmax);

        float sm = e;
#pragma unroll
        for (int off = 1; off < 64; off <<= 1)
            sm += __shfl_xor(sm, off, 64);
        if (lane == 0) wsum[w] = sm;

        // ---- pass B: distributed reduce of e*u_row across the wave ------
        float4 c8[8];
#pragma unroll
        for (int jj = 0; jj < 8; ++jj) {
            const bool up = (lane & 32) != 0;
            float4 keep = up ? u4[jj + 8] : u4[jj];
            float4 give = up ? u4[jj] : u4[jj + 8];
            float4 g; g.x = give.x * e; g.y = give.y * e;
                      g.z = give.z * e; g.w = give.w * e;
            float4 r = shfl_xor4(g, 32);
            float4 o;
            o.x = fmaf(keep.x, e, r.x); o.y = fmaf(keep.y, e, r.y);
            o.z = fmaf(keep.z, e, r.z); o.w = fmaf(keep.w, e, r.w);
            c8[jj] = o;
        }
        float4 c4[4];
#pragma unroll
        for (int jj = 0; jj < 4; ++jj) {
            const bool up = (lane & 16) != 0;
            float4 keep = up ? c8[jj + 4] : c8[jj];
            float4 give = up ? c8[jj] : c8[jj + 4];
            c4[jj] = add4(keep, shfl_xor4(give, 16));
        }
        float4 c2[2];
#pragma unroll
        for (int jj = 0; jj < 2; ++jj) {
            const bool up = (lane & 8) != 0;
            float4 keep = up ? c4[jj + 2] : c4[jj];
            float4 give = up ? c4[jj] : c4[jj + 2];
            c2[jj] = add4(keep, shfl_xor4(give, 8));
        }
        float4 c1;
        {
            const bool up = (lane & 4) != 0;
            float4 keep = up ? c2[1] : c2[0];
            float4 give = up ? c2[0] : c2[1];
            c1 = add4(keep, shfl_xor4(give, 4));
        }
        float p0, p1;
        {
            const bool up = (lane & 2) != 0;
            float kx = up ? c1.z : c1.x, gx = up ? c1.x : c1.z;
            float ky = up ? c1.w : c1.y, gy = up ? c1.y : c1.w;
            p0 = kx + __shfl_xor(gx, 2, 64);
            p1 = ky + __shfl_xor(gy, 2, 64);
        }
        float s_part;
        {
            const bool up = (lane & 1) != 0;
            float k1 = up ? p1 : p0, g1 = up ? p0 : p1;
            s_part = k1 + __shfl_xor(g1, 1, 64);
        }
        partial[(w << 6) + lane] = s_part;
        __syncthreads();

        // ---- combine + tanh + squash (wave 0) ---------------------------
        if (tid < 64) {
            const float inv = 1.0f / (wsum[0] + wsum[1] + wsum[2]
                                    + wsum[3] + wsum[4]);
            float sraw = (partial[tid] + partial[64 + tid] + partial[128 + tid]
                        + partial[192 + tid] + partial[256 + tid]) * inv;
            float s  = tanhf(sraw);
            float ss = s * s;
#pragma unroll
            for (int off = 1; off < 64; off <<= 1)
                ss += __shfl_xor(ss, off, 64);
            float n = sqrtf(ss) + EPSF;
            m_lds[tid] = s * n / (1.0f + n * n);
        }
        __syncthreads();
    }

    if (tid < 64)
        out[(((size_t)b * Mdim + i) << 6) + tid] = m_lds[tid];
}

// ---------------------------------------------------------------------------
extern "C" void kernel_launch(void* const* d_in, const int* in_sizes, int n_in,
                              void* d_out, int out_size, void* d_ws, size_t ws_size,
                              hipStream_t stream) {
    const float* M_emb  = (const float*)d_in[0];
    const float* Ht     = (const float*)d_in[1];
    const float* m_init = (const float*)d_in[2];
    const float* W      = (const float*)d_in[3];
    float* out = (float*)d_out;
    float* u   = (float*)d_ws;

    const size_t per_i = (size_t)Bdim * MTdim * Ddim * sizeof(float);
    int icap = (int)(ws_size / per_i);
    if (icap > Mdim) icap = Mdim;
    if (icap < 1) icap = 1;

    for (int i0 = 0; i0 < Mdim; i0 += icap) {
        int ic = Mdim - i0 < icap ? Mdim - i0 : icap;
        dim3 g1(MTdim, ic);
        u_kernel<<<g1, dim3(256), 0, stream>>>(M_emb, Ht, W, u, i0, icap);
        dim3 g2(ic, Bdim);
        iter_kernel<<<g2, dim3(320), 0, stream>>>(u, m_init, out, i0, icap);
    }
}